// Round 3
// baseline (572.932 us; speedup 1.0000x reference)
//
#include <hip/hip_runtime.h>
#include <stdint.h>

typedef unsigned short u16;
typedef unsigned int u32;
typedef __attribute__((ext_vector_type(8))) short short8;   // 8 bf16 (4 VGPRs)
typedef __attribute__((ext_vector_type(4))) float f32x4;    // MFMA acc
typedef __attribute__((ext_vector_type(4))) u32 u32x4;

__device__ __forceinline__ u16 f2bf(float f) {              // RNE f32->bf16
    u32 x = __float_as_uint(f);
    u32 r = x + 0x7FFFu + ((x >> 16) & 1u);
    return (u16)(r >> 16);
}
__device__ __forceinline__ u32 pack2bf(float a, float b) {
    return (u32)f2bf(a) | ((u32)f2bf(b) << 16);
}
__device__ __forceinline__ float bflo(u32 w) { return __uint_as_float(w << 16); }
__device__ __forceinline__ float bfhi(u32 w) { return __uint_as_float(w & 0xFFFF0000u); }

// ======================= fused prep kernel =======================
// Blocks [0,eg4): hist+rank, 4 edges/thread (8 atomics in flight).
// Blocks [eg4,eg4+cg): f32->bf16 feature conversion (rides in hist's shadow).
// Blocks [eg4+cg, +64): weight prep (4 stacks x 64 units of 64 lanes).
struct WPtrs {
    const float* wl[4];
    const float* wr[4];
    u16* wout[4];
};

__global__ __launch_bounds__(256)
void prep_kernel(const int* __restrict__ src, const int* __restrict__ dst,
                 int* __restrict__ cnt, int* __restrict__ ranku,
                 int* __restrict__ rankm, int E, int nu, int nm,
                 const float* __restrict__ xu, const float* __restrict__ xm,
                 u32* __restrict__ xub, u32* __restrict__ xmb,
                 int eg4, int cg, WPtrs wp) {
    const int bid = blockIdx.x;
    const int tid = threadIdx.x;
    if (bid < eg4) {
        // ---- hist + rank: atomic return value IS the within-segment rank ----
        const int e0 = bid * 1024 + tid;
        int sv[4], dv[4];
        bool ok[4];
#pragma unroll
        for (int k = 0; k < 4; ++k) {
            int e = e0 + k * 256;
            ok[k] = (e < E);
            if (ok[k]) { sv[k] = src[e]; dv[k] = dst[e]; }
        }
#pragma unroll
        for (int k = 0; k < 4; ++k) {
            int e = e0 + k * 256;
            if (ok[k]) {
                if ((unsigned)sv[k] < (unsigned)nu &&
                    (unsigned)dv[k] < (unsigned)nm) {
                    ranku[e] = atomicAdd(&cnt[sv[k]], 1);
                    rankm[e] = atomicAdd(&cnt[nu + dv[k]], 1);
                } else {
                    ranku[e] = -1;
                }
            }
        }
    } else if (bid < eg4 + cg) {
        // ---- f32 [.][128] -> packed bf16 u32 [.][64]; 4 u32 per thread ----
        const int id = (bid - eg4) * 1024 + tid * 4;
        const int nuc = nu * 64;
        const int tot = nuc + nm * 64;   // both multiples of 4: no straddle
        if (id < tot) {
            const float* fin;
            u32* fout;
            int rel;
            if (id < nuc) { fin = xu; fout = xub; rel = id; }
            else          { fin = xm; fout = xmb; rel = id - nuc; }
            float4 p0 = ((const float4*)fin)[(rel >> 1)];
            float4 p1 = ((const float4*)fin)[(rel >> 1) + 1];
            u32x4 o = { pack2bf(p0.x, p0.y), pack2bf(p0.z, p0.w),
                        pack2bf(p1.x, p1.y), pack2bf(p1.z, p1.w) };
            *(u32x4*)(fout + rel) = o;
        }
    } else {
        // ---- wprep: W_stack=[Wl;Wr] (256x128 f32) -> bf16 MFMA-B-fragment
        // order. unit=(stack,tile t,step s); B[k=s*32+(l>>4)*8+j][n=t*16+(l&15)]
        const int unit = (bid - eg4 - cg) * 4 + (tid >> 6);
        if (unit < 256) {
            const int stack = unit >> 6, r = unit & 63, t = r >> 3, s = r & 7;
            const int lane = tid & 63;
            const float* Wl = wp.wl[stack];
            const float* Wr = wp.wr[stack];
            u16* outw = wp.wout[stack];
            const int n = t * 16 + (lane & 15);
            const int k0 = s * 32 + (lane >> 4) * 8;
            u16 v[8];
#pragma unroll
            for (int j = 0; j < 8; ++j) {
                int k = k0 + j;
                float f = (k < 128) ? Wl[k * 128 + n] : Wr[(k - 128) * 128 + n];
                v[j] = f2bf(f);
            }
            *(short8*)(outw + ((size_t)(t * 8 + s) * 64 + lane) * 8) = *(short8*)v;
        }
    }
}

// ======================= scan (partial sums, then apply+top fused) =========
__global__ __launch_bounds__(256)
void scan_partial(const int* __restrict__ cnt, int* __restrict__ bsum, int n) {
    __shared__ int s[256];
    const int tid = threadIdx.x;
    int base = blockIdx.x * 4096 + tid * 16;
    int sum = 0;
#pragma unroll
    for (int k = 0; k < 16; ++k) {
        int i = base + k;
        if (i < n) sum += cnt[i];
    }
    s[tid] = sum;
    __syncthreads();
    for (int d = 128; d > 0; d >>= 1) {
        if (tid < d) s[tid] += s[tid + d];
        __syncthreads();
    }
    if (tid == 0) bsum[blockIdx.x] = s[0];
}

// Each block redoes the tiny (nb<=64) top-level prefix itself -> no scan_top.
__global__ __launch_bounds__(256)
void scan_apply(const int* __restrict__ cnt, const int* __restrict__ bsum,
                int* __restrict__ off, int n, int nb) {
    __shared__ int s[256];
    __shared__ int sb[64];
    __shared__ int pfx;
    const int tid = threadIdx.x;
    int base = blockIdx.x * 4096 + tid * 16;
    int v[16];
    int sum = 0;
#pragma unroll
    for (int k = 0; k < 16; ++k) {
        int i = base + k;
        v[k] = (i < n) ? cnt[i] : 0;
        sum += v[k];
    }
    s[tid] = sum;
    if (tid < 64) sb[tid] = (tid < nb) ? bsum[tid] : 0;
    __syncthreads();
    for (int d = 1; d < 256; d <<= 1) {
        int t = (tid >= d) ? s[tid - d] : 0;
        __syncthreads();
        s[tid] += t;
        __syncthreads();
    }
    if (tid == 0) {
        int p = 0;
        for (int b2 = 0; b2 < (int)blockIdx.x; ++b2) p += sb[b2];
        pfx = p;
        if ((int)blockIdx.x == nb - 1) off[n] = p + s[255];
    }
    __syncthreads();
    int run = pfx + s[tid] - sum;
#pragma unroll
    for (int k = 0; k < 16; ++k) {
        int i = base + k;
        if (i < n) off[i] = run;
        run += v[k];
    }
}

// fill: pure loads + 2 scattered stores (no atomics), 4 edges/thread.
// Unified nbr[2E]: user segs at off[s] in [0,E), movie at off[nu+d] in [E,2E).
__global__ __launch_bounds__(256)
void fill_pos(const int* __restrict__ src, const int* __restrict__ dst,
              const int* __restrict__ ranku, const int* __restrict__ rankm,
              const int* __restrict__ off, int* __restrict__ nbr,
              int E, int nu) {
    const int e0 = blockIdx.x * 1024 + threadIdx.x;
    int sv[4], dv[4], ru[4], rm[4];
#pragma unroll
    for (int k = 0; k < 4; ++k) {
        int e = e0 + k * 256;
        ru[k] = -1;
        if (e < E) {
            ru[k] = ranku[e];
            sv[k] = src[e]; dv[k] = dst[e]; rm[k] = rankm[e];
        }
    }
#pragma unroll
    for (int k = 0; k < 4; ++k) {
        if (ru[k] >= 0) {
            nbr[off[sv[k]] + ru[k]] = dv[k];
            nbr[off[nu + dv[k]] + rm[k]] = sv[k];
        }
    }
}

// ================= fused gather-mean + MFMA node update =================
// 32 nodes/block, 4 waves, 8 nodes/wave in phase 1.
// Gather: dwordx4/lane, 16 lanes per 256B row -> 4 rows per VMEM instr.
// Main loop: 32 edges/iter (8 dwordx4 in flight) with neighbor-index
// prefetch one stage ahead (breaks idx->row dependency chain).
// Cross-slot reduce: 2x shfl_xor(16,32).
// Phase 2: per wave 2 n-tiles x 2 m-tiles (B-frags reused across m-tiles).
// L1=1: out_bf16 = f2bf(x + relu(mean@Wl + b + x@Wr)); x reloaded from
//       L1-hot xf in epilogue. L1=0: out_f32, x staged from bf16 xb.
template <int L1>
__device__ __forceinline__ void fused_body(
    const u32* __restrict__ featb, const float* __restrict__ xf,
    const u32* __restrict__ xb, const int* __restrict__ off,
    const int* __restrict__ nbr, const u16* __restrict__ wt,
    const float* __restrict__ bias, void* __restrict__ outp, int N, int blk) {
    __shared__ u32 sVb[32][132];     // bf16 pairs: k<128 mean, k>=128 x; pad 4
    const int tid = threadIdx.x;
    const int lane = tid & 63;
    const int wave = tid >> 6;
    const int base = blk * 32;
    const int q = lane >> 4;         // row slot (phase1) / D-row quad (phase2)
    const int cl = lane & 15;        // column group (phase1) / D col (phase2)

    // ---- phase 1: gather-mean ----
    for (int c = 0; c < 8; ++c) {
        const int i = wave * 8 + c;
        const int n = base + i;
        if (n < N) {
            const int b = off[n], e = off[n + 1];
            float a0 = 0.f, a1 = 0.f, a2 = 0.f, a3 = 0.f;
            float a4 = 0.f, a5 = 0.f, a6 = 0.f, a7 = 0.f;
            int t = b;
            if (t + 31 < e) {
                int g[8];
#pragma unroll
                for (int k = 0; k < 8; ++k) g[k] = nbr[t + 4 * k + q];
                while (t + 63 < e) {
                    int gn[8];
#pragma unroll
                    for (int k = 0; k < 8; ++k) gn[k] = nbr[t + 32 + 4 * k + q];
#pragma unroll
                    for (int k = 0; k < 8; ++k) {
                        u32x4 v = *(const u32x4*)(featb + (size_t)g[k] * 64 + cl * 4);
                        a0 += bflo(v.x); a1 += bfhi(v.x);
                        a2 += bflo(v.y); a3 += bfhi(v.y);
                        a4 += bflo(v.z); a5 += bfhi(v.z);
                        a6 += bflo(v.w); a7 += bfhi(v.w);
                    }
#pragma unroll
                    for (int k = 0; k < 8; ++k) g[k] = gn[k];
                    t += 32;
                }
                // consume the last prefetched batch (edges t..t+31 valid)
#pragma unroll
                for (int k = 0; k < 8; ++k) {
                    u32x4 v = *(const u32x4*)(featb + (size_t)g[k] * 64 + cl * 4);
                    a0 += bflo(v.x); a1 += bfhi(v.x);
                    a2 += bflo(v.y); a3 += bfhi(v.y);
                    a4 += bflo(v.z); a5 += bfhi(v.z);
                    a6 += bflo(v.w); a7 += bfhi(v.w);
                }
                t += 32;
            }
            for (; t < e; t += 4) {
                int it = t + q;
                if (it < e) {
                    u32x4 v = *(const u32x4*)(featb + (size_t)nbr[it] * 64 + cl * 4);
                    a0 += bflo(v.x); a1 += bfhi(v.x);
                    a2 += bflo(v.y); a3 += bfhi(v.y);
                    a4 += bflo(v.z); a5 += bfhi(v.z);
                    a6 += bflo(v.w); a7 += bfhi(v.w);
                }
            }
            // cross-slot reduce: lanes {x, x+16, x+32, x+48} -> full sums
            a0 += __shfl_xor(a0, 16); a0 += __shfl_xor(a0, 32);
            a1 += __shfl_xor(a1, 16); a1 += __shfl_xor(a1, 32);
            a2 += __shfl_xor(a2, 16); a2 += __shfl_xor(a2, 32);
            a3 += __shfl_xor(a3, 16); a3 += __shfl_xor(a3, 32);
            a4 += __shfl_xor(a4, 16); a4 += __shfl_xor(a4, 32);
            a5 += __shfl_xor(a5, 16); a5 += __shfl_xor(a5, 32);
            a6 += __shfl_xor(a6, 16); a6 += __shfl_xor(a6, 32);
            a7 += __shfl_xor(a7, 16); a7 += __shfl_xor(a7, 32);
            const int dg = e - b;
            const float inv = 1.0f / (float)(dg > 1 ? dg : 1);
            if (q == 0) {
                u32x4 o = { pack2bf(a0 * inv, a1 * inv), pack2bf(a2 * inv, a3 * inv),
                            pack2bf(a4 * inv, a5 * inv), pack2bf(a6 * inv, a7 * inv) };
                *(u32x4*)&sVb[i][cl * 4] = o;     // 16 lanes x 16B = 256B row
            }
            if (L1) {
                const float2 xv = ((const float2*)xf)[(size_t)n * 64 + lane];
                sVb[i][64 + lane] = pack2bf(xv.x, xv.y);
            } else {
                sVb[i][64 + lane] = xb[(size_t)n * 64 + lane];
            }
        } else {
            sVb[i][lane] = 0u;
            sVb[i][64 + lane] = 0u;
        }
    }
    __syncthreads();

    // ---- phase 2: MFMA GEMM (32 nodes x 256 K x 128 out) ----
    const int t0 = wave * 2, t1 = t0 + 1;
    const u16* sVbu = (const u16*)sVb;  // row stride 264 ushort (528 B)
    const short8* wtp = (const short8*)wt;

    f32x4 acc00 = {0.f, 0.f, 0.f, 0.f};
    f32x4 acc01 = {0.f, 0.f, 0.f, 0.f};
    f32x4 acc10 = {0.f, 0.f, 0.f, 0.f};
    f32x4 acc11 = {0.f, 0.f, 0.f, 0.f};
#pragma unroll
    for (int s = 0; s < 8; ++s) {
        short8 a0 = *(const short8*)(sVbu + (size_t)cl * 264 + s * 32 + q * 8);
        short8 a1 = *(const short8*)(sVbu + (size_t)(16 + cl) * 264 + s * 32 + q * 8);
        short8 b0 = wtp[(size_t)(t0 * 8 + s) * 64 + lane];
        short8 b1 = wtp[(size_t)(t1 * 8 + s) * 64 + lane];
        acc00 = __builtin_amdgcn_mfma_f32_16x16x32_bf16(a0, b0, acc00, 0, 0, 0);
        acc01 = __builtin_amdgcn_mfma_f32_16x16x32_bf16(a0, b1, acc01, 0, 0, 0);
        acc10 = __builtin_amdgcn_mfma_f32_16x16x32_bf16(a1, b0, acc10, 0, 0, 0);
        acc11 = __builtin_amdgcn_mfma_f32_16x16x32_bf16(a1, b1, acc11, 0, 0, 0);
    }

    // ---- epilogue: D[m][n], col=lane&15, row=quad*4+reg (+16 for m-tile 1) --
    const int n0 = t0 * 16 + cl, n1 = t1 * 16 + cl;
    const float bj0 = bias[n0], bj1 = bias[n1];
#pragma unroll
    for (int mt = 0; mt < 2; ++mt) {
        const f32x4& c0 = mt ? acc10 : acc00;
        const f32x4& c1 = mt ? acc11 : acc01;
#pragma unroll
        for (int r = 0; r < 4; ++r) {
            const int m = mt * 16 + q * 4 + r;
            const int node = base + m;
            if (node < N) {
                float h0 = c0[r] + bj0;
                float h1 = c1[r] + bj1;
                if (L1) {
                    u16* ob = (u16*)outp;
                    float x0 = xf[(size_t)node * 128 + n0];   // L1-hot reload
                    float x1 = xf[(size_t)node * 128 + n1];
                    ob[(size_t)node * 128 + n0] = f2bf(x0 + fmaxf(h0, 0.f));
                    ob[(size_t)node * 128 + n1] = f2bf(x1 + fmaxf(h1, 0.f));
                } else {
                    float* o = (float*)outp;
                    o[(size_t)node * 128 + n0] = h0;
                    o[(size_t)node * 128 + n1] = h1;
                }
            }
        }
    }
}

__global__ __launch_bounds__(256)
void fused_l1(const u32* __restrict__ featb, const float* __restrict__ xf,
              const int* __restrict__ off, const int* __restrict__ nbr,
              const u16* __restrict__ wt, const float* __restrict__ bias,
              void* __restrict__ outp, int N) {
    fused_body<1>(featb, xf, nullptr, off, nbr, wt, bias, outp, N, blockIdx.x);
}

// Layer-2 pair merged (no aliasing: reads Abf+rmb only, writes d_out only).
__global__ __launch_bounds__(256)
void fused_l2_dual(const u32* __restrict__ Abf, const u32* __restrict__ rmb,
                   const int* __restrict__ off, const int* __restrict__ nbr,
                   const u16* __restrict__ wtm, const u16* __restrict__ wtu,
                   const float* __restrict__ bm, const float* __restrict__ bu,
                   float* __restrict__ outm, float* __restrict__ outu,
                   int nm, int nu, int gm) {
    if ((int)blockIdx.x < gm)
        fused_body<0>(Abf, nullptr, rmb, off + nu, nbr, wtm, bm, outm, nm,
                      blockIdx.x);
    else
        fused_body<0>(rmb, nullptr, Abf, off, nbr, wtu, bu, outu, nu,
                      blockIdx.x - gm);
}

extern "C" void kernel_launch(void* const* d_in, const int* in_sizes, int n_in,
                              void* d_out, int out_size, void* d_ws, size_t ws_size,
                              hipStream_t stream) {
    const int nu = in_sizes[0] / 128;
    const int nm = in_sizes[1] / 128;
    const int E = in_sizes[2];

    const float* xu = (const float*)d_in[0];
    const float* xm = (const float*)d_in[1];
    const int* esrc = (const int*)d_in[2];
    const int* edst = (const int*)d_in[3];
    const float* Wl1_um = (const float*)d_in[4];
    const float* Wr1_um = (const float*)d_in[5];
    const float* Wl1_mu = (const float*)d_in[6];
    const float* Wr1_mu = (const float*)d_in[7];
    const float* Wl2_um = (const float*)d_in[8];
    const float* Wr2_um = (const float*)d_in[9];
    const float* Wl2_mu = (const float*)d_in[10];
    const float* Wr2_mu = (const float*)d_in[11];
    const float* b1_um = (const float*)d_in[12];
    const float* b1_mu = (const float*)d_in[13];
    const float* b2_um = (const float*)d_in[14];
    const float* b2_mu = (const float*)d_in[15];

    float* out_u = (float*)d_out;
    float* out_m = out_u + (size_t)nu * 128;

    // ---- workspace layout (~54 MB; >=62 MB available) ----
    const int ntot = nu + nm;
    const int NB = (ntot + 4095) / 4096;      // <=64 required by scan_apply
    int* cnt = (int*)d_ws;                     // ntot
    int* off = cnt + ntot;                     // ntot+1
    int* bsum = off + ntot + 1;                // NB (padded to 16)
    int* ranku = bsum + ((NB + 15) & ~15);     // E
    int* rankm = ranku + E;                    // E
    int* nbr = rankm + E;                      // 2E
    size_t int_bytes = (size_t)((nbr + 2 * (size_t)E) - (int*)d_ws) * 4;
    size_t wt_off = (int_bytes + 63) & ~(size_t)63;   // 16B-align for short8
    u16* wt1_um = (u16*)((char*)d_ws + wt_off);       // 4 stacks x 32768 u16
    u16* wt1_mu = wt1_um + 32768;
    u16* wt2_um = wt1_mu + 32768;
    u16* wt2_mu = wt2_um + 32768;
    // bf16 feature buffers. Abf holds xu_bf for layer 1, then is overwritten
    // with ru_bf by the L1-user dispatch (xu_bf's last consumer, L1-movie,
    // completes first in stream order).
    u32* Abf = (u32*)((char*)d_ws + wt_off + 4 * 65536);  // nu*64
    u32* xmb = Abf + (size_t)nu * 64;                     // nm*64
    u32* rmb = xmb + (size_t)nm * 64;                     // nm*64

    const int eg4 = (E + 1023) / 1024;
    const int cg = ((nu + nm) * 64 + 1023) / 1024;

    WPtrs wp;
    wp.wl[0] = Wl1_um; wp.wr[0] = Wr1_um; wp.wout[0] = wt1_um;
    wp.wl[1] = Wl1_mu; wp.wr[1] = Wr1_mu; wp.wout[1] = wt1_mu;
    wp.wl[2] = Wl2_um; wp.wr[2] = Wr2_um; wp.wout[2] = wt2_um;
    wp.wl[3] = Wl2_mu; wp.wr[3] = Wr2_mu; wp.wout[3] = wt2_mu;

    // ---- CSR build + prep (hist atomics dominate; conv/wprep ride free) ----
    hipMemsetAsync(cnt, 0, (size_t)ntot * 4, stream);
    prep_kernel<<<eg4 + cg + 64, 256, 0, stream>>>(
        esrc, edst, cnt, ranku, rankm, E, nu, nm, xu, xm, Abf, xmb, eg4, cg, wp);
    scan_partial<<<NB, 256, 0, stream>>>(cnt, bsum, ntot);
    scan_apply<<<NB, 256, 0, stream>>>(cnt, bsum, off, ntot, NB);
    fill_pos<<<eg4, 256, 0, stream>>>(esrc, edst, ranku, rankm, off, nbr, E, nu);

    const int gm = (nm + 31) / 32;
    const int gu = (nu + 31) / 32;

    // ---- layer 1 (bf16-only outputs) ----
    // movie: gather xu_bf (Abf), x = xm f32, write rm_bf
    fused_l1<<<gm, 256, 0, stream>>>(Abf, xm, off + nu, nbr, wt1_um, b1_um,
                                     rmb, nm);
    // user: gather xm_bf, x = xu f32, write ru_bf into Abf (xu_bf now dead)
    fused_l1<<<gu, 256, 0, stream>>>(xmb, xu, off, nbr, wt1_mu, b1_mu,
                                     Abf, nu);

    // ---- layer 2 merged (reads Abf/rmb only; writes d_out only) ----
    fused_l2_dual<<<gm + gu, 256, 0, stream>>>(
        Abf, rmb, off, nbr, wt2_um, wt2_mu, b2_um, b2_mu, out_m, out_u,
        nm, nu, gm);
}

// Round 4
// 513.883 us; speedup vs baseline: 1.1149x; 1.1149x over previous
//
#include <hip/hip_runtime.h>
#include <stdint.h>

typedef unsigned short u16;
typedef unsigned int u32;
typedef __attribute__((ext_vector_type(8))) short short8;   // 8 bf16 (4 VGPRs)
typedef __attribute__((ext_vector_type(4))) float f32x4;    // MFMA acc
typedef __attribute__((ext_vector_type(4))) u32 u32x4;

__device__ __forceinline__ u16 f2bf(float f) {              // RNE f32->bf16
    u32 x = __float_as_uint(f);
    u32 r = x + 0x7FFFu + ((x >> 16) & 1u);
    return (u16)(r >> 16);
}
__device__ __forceinline__ u32 pack2bf(float a, float b) {
    return (u32)f2bf(a) | ((u32)f2bf(b) << 16);
}
__device__ __forceinline__ float bflo(u32 w) { return __uint_as_float(w << 16); }
__device__ __forceinline__ float bfhi(u32 w) { return __uint_as_float(w & 0xFFFF0000u); }

// ======================= fused prep kernel =======================
// Blocks [0,eg4): hist+rank, 4 edges/thread (8 atomics in flight).
// Blocks [eg4,eg4+cg): f32->bf16 feature conversion (rides in hist's shadow).
// Blocks [eg4+cg, +64): weight prep (4 stacks x 64 units of 64 lanes).
struct WPtrs {
    const float* wl[4];
    const float* wr[4];
    u16* wout[4];
};

__global__ __launch_bounds__(256)
void prep_kernel(const int* __restrict__ src, const int* __restrict__ dst,
                 int* __restrict__ cnt, int* __restrict__ ranku,
                 int* __restrict__ rankm, int E, int nu, int nm,
                 const float* __restrict__ xu, const float* __restrict__ xm,
                 u32* __restrict__ xub, u32* __restrict__ xmb,
                 int eg4, int cg, WPtrs wp) {
    const int bid = blockIdx.x;
    const int tid = threadIdx.x;
    if (bid < eg4) {
        // ---- hist + rank: atomic return value IS the within-segment rank ----
        const int e0 = bid * 1024 + tid;
        int sv[4], dv[4];
        bool ok[4];
#pragma unroll
        for (int k = 0; k < 4; ++k) {
            int e = e0 + k * 256;
            ok[k] = (e < E);
            if (ok[k]) { sv[k] = src[e]; dv[k] = dst[e]; }
        }
#pragma unroll
        for (int k = 0; k < 4; ++k) {
            int e = e0 + k * 256;
            if (ok[k]) {
                if ((unsigned)sv[k] < (unsigned)nu &&
                    (unsigned)dv[k] < (unsigned)nm) {
                    ranku[e] = atomicAdd(&cnt[sv[k]], 1);
                    rankm[e] = atomicAdd(&cnt[nu + dv[k]], 1);
                } else {
                    ranku[e] = -1;
                }
            }
        }
    } else if (bid < eg4 + cg) {
        // ---- f32 [.][128] -> packed bf16 u32 [.][64]; 4 u32 per thread ----
        const int id = (bid - eg4) * 1024 + tid * 4;
        const int nuc = nu * 64;
        const int tot = nuc + nm * 64;   // both multiples of 4: no straddle
        if (id < tot) {
            const float* fin;
            u32* fout;
            int rel;
            if (id < nuc) { fin = xu; fout = xub; rel = id; }
            else          { fin = xm; fout = xmb; rel = id - nuc; }
            float4 p0 = ((const float4*)fin)[(rel >> 1)];
            float4 p1 = ((const float4*)fin)[(rel >> 1) + 1];
            u32x4 o = { pack2bf(p0.x, p0.y), pack2bf(p0.z, p0.w),
                        pack2bf(p1.x, p1.y), pack2bf(p1.z, p1.w) };
            *(u32x4*)(fout + rel) = o;
        }
    } else {
        // ---- wprep: W_stack=[Wl;Wr] (256x128 f32) -> bf16 MFMA-B-fragment
        // order. unit=(stack,tile t,step s); B[k=s*32+(l>>4)*8+j][n=t*16+(l&15)]
        const int unit = (bid - eg4 - cg) * 4 + (tid >> 6);
        if (unit < 256) {
            const int stack = unit >> 6, r = unit & 63, t = r >> 3, s = r & 7;
            const int lane = tid & 63;
            const float* Wl = wp.wl[stack];
            const float* Wr = wp.wr[stack];
            u16* outw = wp.wout[stack];
            const int n = t * 16 + (lane & 15);
            const int k0 = s * 32 + (lane >> 4) * 8;
            u16 v[8];
#pragma unroll
            for (int j = 0; j < 8; ++j) {
                int k = k0 + j;
                float f = (k < 128) ? Wl[k * 128 + n] : Wr[(k - 128) * 128 + n];
                v[j] = f2bf(f);
            }
            *(short8*)(outw + ((size_t)(t * 8 + s) * 64 + lane) * 8) = *(short8*)v;
        }
    }
}

// ======================= scan (partial sums, then apply+top fused) =========
__global__ __launch_bounds__(256)
void scan_partial(const int* __restrict__ cnt, int* __restrict__ bsum, int n) {
    __shared__ int s[256];
    const int tid = threadIdx.x;
    int base = blockIdx.x * 4096 + tid * 16;
    int sum = 0;
#pragma unroll
    for (int k = 0; k < 16; ++k) {
        int i = base + k;
        if (i < n) sum += cnt[i];
    }
    s[tid] = sum;
    __syncthreads();
    for (int d = 128; d > 0; d >>= 1) {
        if (tid < d) s[tid] += s[tid + d];
        __syncthreads();
    }
    if (tid == 0) bsum[blockIdx.x] = s[0];
}

// Each block redoes the tiny (nb<=64) top-level prefix itself -> no scan_top.
__global__ __launch_bounds__(256)
void scan_apply(const int* __restrict__ cnt, const int* __restrict__ bsum,
                int* __restrict__ off, int n, int nb) {
    __shared__ int s[256];
    __shared__ int sb[64];
    __shared__ int pfx;
    const int tid = threadIdx.x;
    int base = blockIdx.x * 4096 + tid * 16;
    int v[16];
    int sum = 0;
#pragma unroll
    for (int k = 0; k < 16; ++k) {
        int i = base + k;
        v[k] = (i < n) ? cnt[i] : 0;
        sum += v[k];
    }
    s[tid] = sum;
    if (tid < 64) sb[tid] = (tid < nb) ? bsum[tid] : 0;
    __syncthreads();
    for (int d = 1; d < 256; d <<= 1) {
        int t = (tid >= d) ? s[tid - d] : 0;
        __syncthreads();
        s[tid] += t;
        __syncthreads();
    }
    if (tid == 0) {
        int p = 0;
        for (int b2 = 0; b2 < (int)blockIdx.x; ++b2) p += sb[b2];
        pfx = p;
        if ((int)blockIdx.x == nb - 1) off[n] = p + s[255];
    }
    __syncthreads();
    int run = pfx + s[tid] - sum;
#pragma unroll
    for (int k = 0; k < 16; ++k) {
        int i = base + k;
        if (i < n) off[i] = run;
        run += v[k];
    }
}

// fill: pure loads + 2 scattered stores (no atomics), 4 edges/thread.
// Unified nbr[2E]: user segs at off[s] in [0,E), movie at off[nu+d] in [E,2E).
__global__ __launch_bounds__(256)
void fill_pos(const int* __restrict__ src, const int* __restrict__ dst,
              const int* __restrict__ ranku, const int* __restrict__ rankm,
              const int* __restrict__ off, int* __restrict__ nbr,
              int E, int nu) {
    const int e0 = blockIdx.x * 1024 + threadIdx.x;
    int sv[4], dv[4], ru[4], rm[4];
#pragma unroll
    for (int k = 0; k < 4; ++k) {
        int e = e0 + k * 256;
        ru[k] = -1;
        if (e < E) {
            ru[k] = ranku[e];
            sv[k] = src[e]; dv[k] = dst[e]; rm[k] = rankm[e];
        }
    }
#pragma unroll
    for (int k = 0; k < 4; ++k) {
        if (ru[k] >= 0) {
            nbr[off[sv[k]] + ru[k]] = dv[k];
            nbr[off[nu + dv[k]] + rm[k]] = sv[k];
        }
    }
}

// ================= fused gather-mean + MFMA node update =================
// 16 nodes/block, 2 waves (128 thr), 8 nodes/wave in phase 1.
// Rationale (round-3 postmortem): gather is latency-bound and hidden by TLP.
// 2-wave blocks: LDS 8.4KB -> 16 blocks/CU x 2 waves = 32 waves/CU
// theoretical; barrier convoy averages over 2 waves not 4. VGPR pinned
// <=64 via __launch_bounds__(128,8) (round-3's 64-VGPR cliff).
// Gather: dwordx4/lane, 16 lanes per 256B row -> 4 rows per VMEM instr,
// 4-way unrolled = 16 rows (4KB) in flight per wave (round-2 proven loop).
// Cross-slot reduce: 2x shfl_xor(16,32).
// Phase 2: per wave 4 n-tiles x 1 m-tile (16 nodes).
// L1=1: out_bf16 = f2bf(x + relu(mean@Wl + b + x@Wr)); x reloaded from
//       L1-hot xf in epilogue. L1=0: out_f32, x staged from bf16 xb.
template <int L1>
__device__ __forceinline__ void fused_body(
    const u32* __restrict__ featb, const float* __restrict__ xf,
    const u32* __restrict__ xb, const int* __restrict__ off,
    const int* __restrict__ nbr, const u16* __restrict__ wt,
    const float* __restrict__ bias, void* __restrict__ outp, int N, int blk) {
    __shared__ u32 sVb[16][132];     // bf16 pairs: k<128 mean, k>=128 x; pad 4
    const int tid = threadIdx.x;
    const int lane = tid & 63;
    const int wave = tid >> 6;       // 0..1
    const int base = blk * 16;
    const int q = lane >> 4;         // row slot (phase1) / D-row quad (phase2)
    const int cl = lane & 15;        // column group (phase1) / D col (phase2)

    // ---- phase 1: gather-mean ----
    for (int c = 0; c < 8; ++c) {
        const int i = wave * 8 + c;
        const int n = base + i;
        if (n < N) {
            const int b = off[n], e = off[n + 1];
            float a0 = 0.f, a1 = 0.f, a2 = 0.f, a3 = 0.f;
            float a4 = 0.f, a5 = 0.f, a6 = 0.f, a7 = 0.f;
            int t = b;
            for (; t + 15 < e; t += 16) {
                int g0 = nbr[t + q];
                int g1 = nbr[t + 4 + q];
                int g2 = nbr[t + 8 + q];
                int g3 = nbr[t + 12 + q];
                u32x4 v0 = *(const u32x4*)(featb + (size_t)g0 * 64 + cl * 4);
                u32x4 v1 = *(const u32x4*)(featb + (size_t)g1 * 64 + cl * 4);
                u32x4 v2 = *(const u32x4*)(featb + (size_t)g2 * 64 + cl * 4);
                u32x4 v3 = *(const u32x4*)(featb + (size_t)g3 * 64 + cl * 4);
                a0 += bflo(v0.x); a1 += bfhi(v0.x); a2 += bflo(v0.y); a3 += bfhi(v0.y);
                a4 += bflo(v0.z); a5 += bfhi(v0.z); a6 += bflo(v0.w); a7 += bfhi(v0.w);
                a0 += bflo(v1.x); a1 += bfhi(v1.x); a2 += bflo(v1.y); a3 += bfhi(v1.y);
                a4 += bflo(v1.z); a5 += bfhi(v1.z); a6 += bflo(v1.w); a7 += bfhi(v1.w);
                a0 += bflo(v2.x); a1 += bfhi(v2.x); a2 += bflo(v2.y); a3 += bfhi(v2.y);
                a4 += bflo(v2.z); a5 += bfhi(v2.z); a6 += bflo(v2.w); a7 += bfhi(v2.w);
                a0 += bflo(v3.x); a1 += bfhi(v3.x); a2 += bflo(v3.y); a3 += bfhi(v3.y);
                a4 += bflo(v3.z); a5 += bfhi(v3.z); a6 += bflo(v3.w); a7 += bfhi(v3.w);
            }
            for (; t < e; t += 4) {
                int it = t + q;
                if (it < e) {
                    u32x4 v = *(const u32x4*)(featb + (size_t)nbr[it] * 64 + cl * 4);
                    a0 += bflo(v.x); a1 += bfhi(v.x); a2 += bflo(v.y); a3 += bfhi(v.y);
                    a4 += bflo(v.z); a5 += bfhi(v.z); a6 += bflo(v.w); a7 += bfhi(v.w);
                }
            }
            // cross-slot reduce: lanes {x, x+16, x+32, x+48} -> full sums
            a0 += __shfl_xor(a0, 16); a0 += __shfl_xor(a0, 32);
            a1 += __shfl_xor(a1, 16); a1 += __shfl_xor(a1, 32);
            a2 += __shfl_xor(a2, 16); a2 += __shfl_xor(a2, 32);
            a3 += __shfl_xor(a3, 16); a3 += __shfl_xor(a3, 32);
            a4 += __shfl_xor(a4, 16); a4 += __shfl_xor(a4, 32);
            a5 += __shfl_xor(a5, 16); a5 += __shfl_xor(a5, 32);
            a6 += __shfl_xor(a6, 16); a6 += __shfl_xor(a6, 32);
            a7 += __shfl_xor(a7, 16); a7 += __shfl_xor(a7, 32);
            const int dg = e - b;
            const float inv = 1.0f / (float)(dg > 1 ? dg : 1);
            if (q == 0) {
                u32x4 o = { pack2bf(a0 * inv, a1 * inv), pack2bf(a2 * inv, a3 * inv),
                            pack2bf(a4 * inv, a5 * inv), pack2bf(a6 * inv, a7 * inv) };
                *(u32x4*)&sVb[i][cl * 4] = o;     // 16 lanes x 16B = 256B row
            }
            if (L1) {
                const float2 xv = ((const float2*)xf)[(size_t)n * 64 + lane];
                sVb[i][64 + lane] = pack2bf(xv.x, xv.y);
            } else {
                sVb[i][64 + lane] = xb[(size_t)n * 64 + lane];
            }
        } else {
            sVb[i][lane] = 0u;
            sVb[i][64 + lane] = 0u;
        }
    }
    __syncthreads();

    // ---- phase 2: MFMA GEMM (16 nodes x 256 K x 128 out), 4 tiles/wave ----
    const int t0 = wave * 4;
    const u16* sVbu = (const u16*)sVb;  // row stride 264 ushort (528 B)
    const short8* wtp = (const short8*)wt;

    f32x4 acc0 = {0.f, 0.f, 0.f, 0.f};
    f32x4 acc1 = {0.f, 0.f, 0.f, 0.f};
    f32x4 acc2 = {0.f, 0.f, 0.f, 0.f};
    f32x4 acc3 = {0.f, 0.f, 0.f, 0.f};
#pragma unroll
    for (int s = 0; s < 8; ++s) {
        short8 a = *(const short8*)(sVbu + (size_t)cl * 264 + s * 32 + q * 8);
        short8 b0 = wtp[(size_t)((t0 + 0) * 8 + s) * 64 + lane];
        short8 b1 = wtp[(size_t)((t0 + 1) * 8 + s) * 64 + lane];
        short8 b2 = wtp[(size_t)((t0 + 2) * 8 + s) * 64 + lane];
        short8 b3 = wtp[(size_t)((t0 + 3) * 8 + s) * 64 + lane];
        acc0 = __builtin_amdgcn_mfma_f32_16x16x32_bf16(a, b0, acc0, 0, 0, 0);
        acc1 = __builtin_amdgcn_mfma_f32_16x16x32_bf16(a, b1, acc1, 0, 0, 0);
        acc2 = __builtin_amdgcn_mfma_f32_16x16x32_bf16(a, b2, acc2, 0, 0, 0);
        acc3 = __builtin_amdgcn_mfma_f32_16x16x32_bf16(a, b3, acc3, 0, 0, 0);
    }

    // ---- epilogue: D[m][n], col=lane&15, row=quad*4+reg ----
#pragma unroll
    for (int tt = 0; tt < 4; ++tt) {
        const f32x4& cc = tt == 0 ? acc0 : tt == 1 ? acc1 : tt == 2 ? acc2 : acc3;
        const int nn = (t0 + tt) * 16 + cl;
        const float bj = bias[nn];
#pragma unroll
        for (int r = 0; r < 4; ++r) {
            const int m = q * 4 + r;
            const int node = base + m;
            if (node < N) {
                float h = cc[r] + bj;
                if (L1) {
                    u16* ob = (u16*)outp;
                    float x0 = xf[(size_t)node * 128 + nn];   // L1-hot reload
                    ob[(size_t)node * 128 + nn] = f2bf(x0 + fmaxf(h, 0.f));
                } else {
                    float* o = (float*)outp;
                    o[(size_t)node * 128 + nn] = h;
                }
            }
        }
    }
}

__global__ __launch_bounds__(128, 8)
void fused_l1(const u32* __restrict__ featb, const float* __restrict__ xf,
              const int* __restrict__ off, const int* __restrict__ nbr,
              const u16* __restrict__ wt, const float* __restrict__ bias,
              void* __restrict__ outp, int N) {
    fused_body<1>(featb, xf, nullptr, off, nbr, wt, bias, outp, N, blockIdx.x);
}

// Layer-2 pair merged (no aliasing: reads Abf+rmb only, writes d_out only).
__global__ __launch_bounds__(128, 8)
void fused_l2_dual(const u32* __restrict__ Abf, const u32* __restrict__ rmb,
                   const int* __restrict__ off, const int* __restrict__ nbr,
                   const u16* __restrict__ wtm, const u16* __restrict__ wtu,
                   const float* __restrict__ bm, const float* __restrict__ bu,
                   float* __restrict__ outm, float* __restrict__ outu,
                   int nm, int nu, int gm) {
    if ((int)blockIdx.x < gm)
        fused_body<0>(Abf, nullptr, rmb, off + nu, nbr, wtm, bm, outm, nm,
                      blockIdx.x);
    else
        fused_body<0>(rmb, nullptr, Abf, off, nbr, wtu, bu, outu, nu,
                      blockIdx.x - gm);
}

extern "C" void kernel_launch(void* const* d_in, const int* in_sizes, int n_in,
                              void* d_out, int out_size, void* d_ws, size_t ws_size,
                              hipStream_t stream) {
    const int nu = in_sizes[0] / 128;
    const int nm = in_sizes[1] / 128;
    const int E = in_sizes[2];

    const float* xu = (const float*)d_in[0];
    const float* xm = (const float*)d_in[1];
    const int* esrc = (const int*)d_in[2];
    const int* edst = (const int*)d_in[3];
    const float* Wl1_um = (const float*)d_in[4];
    const float* Wr1_um = (const float*)d_in[5];
    const float* Wl1_mu = (const float*)d_in[6];
    const float* Wr1_mu = (const float*)d_in[7];
    const float* Wl2_um = (const float*)d_in[8];
    const float* Wr2_um = (const float*)d_in[9];
    const float* Wl2_mu = (const float*)d_in[10];
    const float* Wr2_mu = (const float*)d_in[11];
    const float* b1_um = (const float*)d_in[12];
    const float* b1_mu = (const float*)d_in[13];
    const float* b2_um = (const float*)d_in[14];
    const float* b2_mu = (const float*)d_in[15];

    float* out_u = (float*)d_out;
    float* out_m = out_u + (size_t)nu * 128;

    // ---- workspace layout (~54 MB; >=62 MB available) ----
    const int ntot = nu + nm;
    const int NB = (ntot + 4095) / 4096;      // <=64 required by scan_apply
    int* cnt = (int*)d_ws;                     // ntot
    int* off = cnt + ntot;                     // ntot+1
    int* bsum = off + ntot + 1;                // NB (padded to 16)
    int* ranku = bsum + ((NB + 15) & ~15);     // E
    int* rankm = ranku + E;                    // E
    int* nbr = rankm + E;                      // 2E
    size_t int_bytes = (size_t)((nbr + 2 * (size_t)E) - (int*)d_ws) * 4;
    size_t wt_off = (int_bytes + 63) & ~(size_t)63;   // 16B-align for short8
    u16* wt1_um = (u16*)((char*)d_ws + wt_off);       // 4 stacks x 32768 u16
    u16* wt1_mu = wt1_um + 32768;
    u16* wt2_um = wt1_mu + 32768;
    u16* wt2_mu = wt2_um + 32768;
    // bf16 feature buffers. Abf holds xu_bf for layer 1, then is overwritten
    // with ru_bf by the L1-user dispatch (xu_bf's last consumer, L1-movie,
    // completes first in stream order).
    u32* Abf = (u32*)((char*)d_ws + wt_off + 4 * 65536);  // nu*64
    u32* xmb = Abf + (size_t)nu * 64;                     // nm*64
    u32* rmb = xmb + (size_t)nm * 64;                     // nm*64

    const int eg4 = (E + 1023) / 1024;
    const int cg = ((nu + nm) * 64 + 1023) / 1024;

    WPtrs wp;
    wp.wl[0] = Wl1_um; wp.wr[0] = Wr1_um; wp.wout[0] = wt1_um;
    wp.wl[1] = Wl1_mu; wp.wr[1] = Wr1_mu; wp.wout[1] = wt1_mu;
    wp.wl[2] = Wl2_um; wp.wr[2] = Wr2_um; wp.wout[2] = wt2_um;
    wp.wl[3] = Wl2_mu; wp.wr[3] = Wr2_mu; wp.wout[3] = wt2_mu;

    // ---- CSR build + prep (hist atomics dominate; conv/wprep ride free) ----
    hipMemsetAsync(cnt, 0, (size_t)ntot * 4, stream);
    prep_kernel<<<eg4 + cg + 64, 256, 0, stream>>>(
        esrc, edst, cnt, ranku, rankm, E, nu, nm, xu, xm, Abf, xmb, eg4, cg, wp);
    scan_partial<<<NB, 256, 0, stream>>>(cnt, bsum, ntot);
    scan_apply<<<NB, 256, 0, stream>>>(cnt, bsum, off, ntot, NB);
    fill_pos<<<eg4, 256, 0, stream>>>(esrc, edst, ranku, rankm, off, nbr, E, nu);

    const int gm = (nm + 15) / 16;
    const int gu = (nu + 15) / 16;

    // ---- layer 1 (bf16-only outputs) ----
    // movie: gather xu_bf (Abf), x = xm f32, write rm_bf
    fused_l1<<<gm, 128, 0, stream>>>(Abf, xm, off + nu, nbr, wt1_um, b1_um,
                                     rmb, nm);
    // user: gather xm_bf, x = xu f32, write ru_bf into Abf (xu_bf now dead)
    fused_l1<<<gu, 128, 0, stream>>>(xmb, xu, off, nbr, wt1_mu, b1_mu,
                                     Abf, nu);

    // ---- layer 2 merged (reads Abf/rmb only; writes d_out only) ----
    fused_l2_dual<<<gm + gu, 128, 0, stream>>>(
        Abf, rmb, off, nbr, wt2_um, wt2_mu, b2_um, b2_mu, out_m, out_u,
        nm, nu, gm);
}

// Round 5
// 480.536 us; speedup vs baseline: 1.1923x; 1.0694x over previous
//
#include <hip/hip_runtime.h>
#include <stdint.h>

typedef unsigned short u16;
typedef unsigned int u32;
typedef __attribute__((ext_vector_type(8))) short short8;   // 8 bf16 (4 VGPRs)
typedef __attribute__((ext_vector_type(4))) float f32x4;    // MFMA acc
typedef __attribute__((ext_vector_type(4))) u32 u32x4;

__device__ __forceinline__ u16 f2bf(float f) {              // RNE f32->bf16
    u32 x = __float_as_uint(f);
    u32 r = x + 0x7FFFu + ((x >> 16) & 1u);
    return (u16)(r >> 16);
}
__device__ __forceinline__ u32 pack2bf(float a, float b) {
    return (u32)f2bf(a) | ((u32)f2bf(b) << 16);
}
__device__ __forceinline__ float bflo(u32 w) { return __uint_as_float(w << 16); }
__device__ __forceinline__ float bfhi(u32 w) { return __uint_as_float(w & 0xFFFF0000u); }

// ======================= fused prep kernel =======================
// Blocks [0,eg4): hist+rank, 4 edges/thread (8 atomics in flight).
// Blocks [eg4,eg4+cg): f32->bf16 feature conversion (rides in hist's shadow).
// Blocks [eg4+cg, +64): weight prep (4 stacks x 64 units of 64 lanes).
struct WPtrs {
    const float* wl[4];
    const float* wr[4];
    u16* wout[4];
};

__global__ __launch_bounds__(256)
void prep_kernel(const int* __restrict__ src, const int* __restrict__ dst,
                 int* __restrict__ cnt, int* __restrict__ ranku,
                 int* __restrict__ rankm, int E, int nu, int nm,
                 const float* __restrict__ xu, const float* __restrict__ xm,
                 u32* __restrict__ xub, u32* __restrict__ xmb,
                 int eg4, int cg, WPtrs wp) {
    const int bid = blockIdx.x;
    const int tid = threadIdx.x;
    if (bid < eg4) {
        // ---- hist + rank: atomic return value IS the within-segment rank ----
        const int e0 = bid * 1024 + tid;
        int sv[4], dv[4];
        bool ok[4];
#pragma unroll
        for (int k = 0; k < 4; ++k) {
            int e = e0 + k * 256;
            ok[k] = (e < E);
            if (ok[k]) { sv[k] = src[e]; dv[k] = dst[e]; }
        }
#pragma unroll
        for (int k = 0; k < 4; ++k) {
            int e = e0 + k * 256;
            if (ok[k]) {
                if ((unsigned)sv[k] < (unsigned)nu &&
                    (unsigned)dv[k] < (unsigned)nm) {
                    ranku[e] = atomicAdd(&cnt[sv[k]], 1);
                    rankm[e] = atomicAdd(&cnt[nu + dv[k]], 1);
                } else {
                    ranku[e] = -1;
                }
            }
        }
    } else if (bid < eg4 + cg) {
        // ---- f32 [.][128] -> packed bf16 u32 [.][64]; 4 u32 per thread ----
        const int id = (bid - eg4) * 1024 + tid * 4;
        const int nuc = nu * 64;
        const int tot = nuc + nm * 64;   // both multiples of 4: no straddle
        if (id < tot) {
            const float* fin;
            u32* fout;
            int rel;
            if (id < nuc) { fin = xu; fout = xub; rel = id; }
            else          { fin = xm; fout = xmb; rel = id - nuc; }
            float4 p0 = ((const float4*)fin)[(rel >> 1)];
            float4 p1 = ((const float4*)fin)[(rel >> 1) + 1];
            u32x4 o = { pack2bf(p0.x, p0.y), pack2bf(p0.z, p0.w),
                        pack2bf(p1.x, p1.y), pack2bf(p1.z, p1.w) };
            *(u32x4*)(fout + rel) = o;
        }
    } else {
        // ---- wprep: W_stack=[Wl;Wr] (256x128 f32) -> bf16 MFMA-B-fragment
        // order. unit=(stack,tile t,step s); B[k=s*32+(l>>4)*8+j][n=t*16+(l&15)]
        const int unit = (bid - eg4 - cg) * 4 + (tid >> 6);
        if (unit < 256) {
            const int stack = unit >> 6, r = unit & 63, t = r >> 3, s = r & 7;
            const int lane = tid & 63;
            const float* Wl = wp.wl[stack];
            const float* Wr = wp.wr[stack];
            u16* outw = wp.wout[stack];
            const int n = t * 16 + (lane & 15);
            const int k0 = s * 32 + (lane >> 4) * 8;
            u16 v[8];
#pragma unroll
            for (int j = 0; j < 8; ++j) {
                int k = k0 + j;
                float f = (k < 128) ? Wl[k * 128 + n] : Wr[(k - 128) * 128 + n];
                v[j] = f2bf(f);
            }
            *(short8*)(outw + ((size_t)(t * 8 + s) * 64 + lane) * 8) = *(short8*)v;
        }
    }
}

// ======================= scan (partial sums, then apply+top fused) =========
__global__ __launch_bounds__(256)
void scan_partial(const int* __restrict__ cnt, int* __restrict__ bsum, int n) {
    __shared__ int s[256];
    const int tid = threadIdx.x;
    int base = blockIdx.x * 4096 + tid * 16;
    int sum = 0;
#pragma unroll
    for (int k = 0; k < 16; ++k) {
        int i = base + k;
        if (i < n) sum += cnt[i];
    }
    s[tid] = sum;
    __syncthreads();
    for (int d = 128; d > 0; d >>= 1) {
        if (tid < d) s[tid] += s[tid + d];
        __syncthreads();
    }
    if (tid == 0) bsum[blockIdx.x] = s[0];
}

// Each block redoes the tiny (nb<=64) top-level prefix itself -> no scan_top.
__global__ __launch_bounds__(256)
void scan_apply(const int* __restrict__ cnt, const int* __restrict__ bsum,
                int* __restrict__ off, int n, int nb) {
    __shared__ int s[256];
    __shared__ int sb[64];
    __shared__ int pfx;
    const int tid = threadIdx.x;
    int base = blockIdx.x * 4096 + tid * 16;
    int v[16];
    int sum = 0;
#pragma unroll
    for (int k = 0; k < 16; ++k) {
        int i = base + k;
        v[k] = (i < n) ? cnt[i] : 0;
        sum += v[k];
    }
    s[tid] = sum;
    if (tid < 64) sb[tid] = (tid < nb) ? bsum[tid] : 0;
    __syncthreads();
    for (int d = 1; d < 256; d <<= 1) {
        int t = (tid >= d) ? s[tid - d] : 0;
        __syncthreads();
        s[tid] += t;
        __syncthreads();
    }
    if (tid == 0) {
        int p = 0;
        for (int b2 = 0; b2 < (int)blockIdx.x; ++b2) p += sb[b2];
        pfx = p;
        if ((int)blockIdx.x == nb - 1) off[n] = p + s[255];
    }
    __syncthreads();
    int run = pfx + s[tid] - sum;
#pragma unroll
    for (int k = 0; k < 16; ++k) {
        int i = base + k;
        if (i < n) off[i] = run;
        run += v[k];
    }
}

// fill: pure loads + 2 scattered stores (no atomics), 4 edges/thread.
// Unified nbr[2E]: user segs at off[s] in [0,E), movie at off[nu+d] in [E,2E).
__global__ __launch_bounds__(256)
void fill_pos(const int* __restrict__ src, const int* __restrict__ dst,
              const int* __restrict__ ranku, const int* __restrict__ rankm,
              const int* __restrict__ off, int* __restrict__ nbr,
              int E, int nu) {
    const int e0 = blockIdx.x * 1024 + threadIdx.x;
    int sv[4], dv[4], ru[4], rm[4];
#pragma unroll
    for (int k = 0; k < 4; ++k) {
        int e = e0 + k * 256;
        ru[k] = -1;
        if (e < E) {
            ru[k] = ranku[e];
            sv[k] = src[e]; dv[k] = dst[e]; rm[k] = rankm[e];
        }
    }
#pragma unroll
    for (int k = 0; k < 4; ++k) {
        if (ru[k] >= 0) {
            nbr[off[sv[k]] + ru[k]] = dv[k];
            nbr[off[nu + dv[k]] + rm[k]] = sv[k];
        }
    }
}

// ================= fused gather-mean + MFMA node update =================
// 16 nodes/block, 2 waves (128 thr).
// Phase 1 (round-5 restructure): SLOT-PARALLEL gather. q = lane>>4 selects
// one of 4 nodes processed CONCURRENTLY per wave; the slot's 16 lanes (cl)
// each own 16B of the 256B feature row. Per outer iter a slot consumes 4
// edges: 4 idx loads + 4 row loads, all issued unconditionally via
// in-segment clamp min(p+k, e-1); out-of-degree contributions killed by an
// fma mask. Benefits vs round-4: 4 nodes in flight (4x shorter serial
// latency chain on low-degree users), uniform path for all degrees, and the
// 16-shfl cross-slot reduce is gone (slot lanes hold the full row).
// Phase 2: per wave 4 n-tiles x 1 m-tile (16 nodes) - unchanged.
// L1=1: out_bf16 = f2bf(x + relu(mean@Wl + b + x@Wr)); x reloaded from
//       L1-hot xf in epilogue. L1=0: out_f32, x staged from bf16 xb.
template <int L1>
__device__ __forceinline__ void fused_body(
    const u32* __restrict__ featb, const float* __restrict__ xf,
    const u32* __restrict__ xb, const int* __restrict__ off,
    const int* __restrict__ nbr, const u16* __restrict__ wt,
    const float* __restrict__ bias, void* __restrict__ outp, int N, int blk) {
    __shared__ u32 sVb[16][132];     // bf16 pairs: k<128 mean, k>=128 x; pad 4
    const int tid = threadIdx.x;
    const int lane = tid & 63;
    const int wave = tid >> 6;       // 0..1
    const int base = blk * 16;
    const int q = lane >> 4;         // node slot (phase1) / D-row quad (phase2)
    const int cl = lane & 15;        // channel group (phase1) / D col (phase2)

    // ---- phase 1: slot-parallel gather-mean (2 quads of 4 nodes / wave) ----
#pragma unroll
    for (int gg = 0; gg < 2; ++gg) {
        const int i = wave * 8 + gg * 4 + q;   // node-local index 0..15
        const int n = base + i;
        int b = 0, e2 = 0;
        if (n < N) { b = off[n]; e2 = off[n + 1]; }
        const int deg = e2 - b;
        float a0 = 0.f, a1 = 0.f, a2 = 0.f, a3 = 0.f;
        float a4 = 0.f, a5 = 0.f, a6 = 0.f, a7 = 0.f;
        for (int j = 0; j < deg; j += 4) {
            const int p = b + j;
            // clamped in-segment positions: always-valid, branch-free issue
            const int p1 = (p + 1 < e2) ? p + 1 : e2 - 1;
            const int p2 = (p + 2 < e2) ? p + 2 : e2 - 1;
            const int p3 = (p + 3 < e2) ? p + 3 : e2 - 1;
            const float m1 = (p + 1 < e2) ? 1.f : 0.f;
            const float m2 = (p + 2 < e2) ? 1.f : 0.f;
            const float m3 = (p + 3 < e2) ? 1.f : 0.f;
            const int g0 = nbr[p];
            const int g1 = nbr[p1];
            const int g2 = nbr[p2];
            const int g3 = nbr[p3];
            u32x4 v0 = *(const u32x4*)(featb + (size_t)g0 * 64 + cl * 4);
            u32x4 v1 = *(const u32x4*)(featb + (size_t)g1 * 64 + cl * 4);
            u32x4 v2 = *(const u32x4*)(featb + (size_t)g2 * 64 + cl * 4);
            u32x4 v3 = *(const u32x4*)(featb + (size_t)g3 * 64 + cl * 4);
            a0 += bflo(v0.x); a1 += bfhi(v0.x); a2 += bflo(v0.y); a3 += bfhi(v0.y);
            a4 += bflo(v0.z); a5 += bfhi(v0.z); a6 += bflo(v0.w); a7 += bfhi(v0.w);
            a0 = fmaf(bflo(v1.x), m1, a0); a1 = fmaf(bfhi(v1.x), m1, a1);
            a2 = fmaf(bflo(v1.y), m1, a2); a3 = fmaf(bfhi(v1.y), m1, a3);
            a4 = fmaf(bflo(v1.z), m1, a4); a5 = fmaf(bfhi(v1.z), m1, a5);
            a6 = fmaf(bflo(v1.w), m1, a6); a7 = fmaf(bfhi(v1.w), m1, a7);
            a0 = fmaf(bflo(v2.x), m2, a0); a1 = fmaf(bfhi(v2.x), m2, a1);
            a2 = fmaf(bflo(v2.y), m2, a2); a3 = fmaf(bfhi(v2.y), m2, a3);
            a4 = fmaf(bflo(v2.z), m2, a4); a5 = fmaf(bfhi(v2.z), m2, a5);
            a6 = fmaf(bflo(v2.w), m2, a6); a7 = fmaf(bfhi(v2.w), m2, a7);
            a0 = fmaf(bflo(v3.x), m3, a0); a1 = fmaf(bfhi(v3.x), m3, a1);
            a2 = fmaf(bflo(v3.y), m3, a2); a3 = fmaf(bfhi(v3.y), m3, a3);
            a4 = fmaf(bflo(v3.z), m3, a4); a5 = fmaf(bfhi(v3.z), m3, a5);
            a6 = fmaf(bflo(v3.w), m3, a6); a7 = fmaf(bfhi(v3.w), m3, a7);
        }
        const float inv = 1.0f / (float)(deg > 1 ? deg : 1);
        u32x4 o = { pack2bf(a0 * inv, a1 * inv), pack2bf(a2 * inv, a3 * inv),
                    pack2bf(a4 * inv, a5 * inv), pack2bf(a6 * inv, a7 * inv) };
        *(u32x4*)&sVb[i][cl * 4] = o;     // slot's 16 lanes = full 256B row
    }
    // ---- x staging (full-wave coalesced rows, 8 nodes/wave) ----
    for (int c = 0; c < 8; ++c) {
        const int i = wave * 8 + c;
        const int n = base + i;
        if (n < N) {
            if (L1) {
                const float2 xv = ((const float2*)xf)[(size_t)n * 64 + lane];
                sVb[i][64 + lane] = pack2bf(xv.x, xv.y);
            } else {
                sVb[i][64 + lane] = xb[(size_t)n * 64 + lane];
            }
        } else {
            sVb[i][64 + lane] = 0u;
        }
    }
    __syncthreads();

    // ---- phase 2: MFMA GEMM (16 nodes x 256 K x 128 out), 4 tiles/wave ----
    const int t0 = wave * 4;
    const u16* sVbu = (const u16*)sVb;  // row stride 264 ushort (528 B)
    const short8* wtp = (const short8*)wt;

    f32x4 acc0 = {0.f, 0.f, 0.f, 0.f};
    f32x4 acc1 = {0.f, 0.f, 0.f, 0.f};
    f32x4 acc2 = {0.f, 0.f, 0.f, 0.f};
    f32x4 acc3 = {0.f, 0.f, 0.f, 0.f};
#pragma unroll
    for (int s = 0; s < 8; ++s) {
        short8 a = *(const short8*)(sVbu + (size_t)cl * 264 + s * 32 + q * 8);
        short8 b0 = wtp[(size_t)((t0 + 0) * 8 + s) * 64 + lane];
        short8 b1 = wtp[(size_t)((t0 + 1) * 8 + s) * 64 + lane];
        short8 b2 = wtp[(size_t)((t0 + 2) * 8 + s) * 64 + lane];
        short8 b3 = wtp[(size_t)((t0 + 3) * 8 + s) * 64 + lane];
        acc0 = __builtin_amdgcn_mfma_f32_16x16x32_bf16(a, b0, acc0, 0, 0, 0);
        acc1 = __builtin_amdgcn_mfma_f32_16x16x32_bf16(a, b1, acc1, 0, 0, 0);
        acc2 = __builtin_amdgcn_mfma_f32_16x16x32_bf16(a, b2, acc2, 0, 0, 0);
        acc3 = __builtin_amdgcn_mfma_f32_16x16x32_bf16(a, b3, acc3, 0, 0, 0);
    }

    // ---- epilogue: D[m][n], col=lane&15, row=quad*4+reg ----
#pragma unroll
    for (int tt = 0; tt < 4; ++tt) {
        const f32x4& cc = tt == 0 ? acc0 : tt == 1 ? acc1 : tt == 2 ? acc2 : acc3;
        const int nn = (t0 + tt) * 16 + cl;
        const float bj = bias[nn];
#pragma unroll
        for (int r = 0; r < 4; ++r) {
            const int m = q * 4 + r;
            const int node = base + m;
            if (node < N) {
                float h = cc[r] + bj;
                if (L1) {
                    u16* ob = (u16*)outp;
                    float x0 = xf[(size_t)node * 128 + nn];   // L1-hot reload
                    ob[(size_t)node * 128 + nn] = f2bf(x0 + fmaxf(h, 0.f));
                } else {
                    float* o = (float*)outp;
                    o[(size_t)node * 128 + nn] = h;
                }
            }
        }
    }
}

__global__ __launch_bounds__(128, 8)
void fused_l1(const u32* __restrict__ featb, const float* __restrict__ xf,
              const int* __restrict__ off, const int* __restrict__ nbr,
              const u16* __restrict__ wt, const float* __restrict__ bias,
              void* __restrict__ outp, int N) {
    fused_body<1>(featb, xf, nullptr, off, nbr, wt, bias, outp, N, blockIdx.x);
}

// Layer-2 pair merged (no aliasing: reads Abf+rmb only, writes d_out only).
__global__ __launch_bounds__(128, 8)
void fused_l2_dual(const u32* __restrict__ Abf, const u32* __restrict__ rmb,
                   const int* __restrict__ off, const int* __restrict__ nbr,
                   const u16* __restrict__ wtm, const u16* __restrict__ wtu,
                   const float* __restrict__ bm, const float* __restrict__ bu,
                   float* __restrict__ outm, float* __restrict__ outu,
                   int nm, int nu, int gm) {
    if ((int)blockIdx.x < gm)
        fused_body<0>(Abf, nullptr, rmb, off + nu, nbr, wtm, bm, outm, nm,
                      blockIdx.x);
    else
        fused_body<0>(rmb, nullptr, Abf, off, nbr, wtu, bu, outu, nu,
                      blockIdx.x - gm);
}

extern "C" void kernel_launch(void* const* d_in, const int* in_sizes, int n_in,
                              void* d_out, int out_size, void* d_ws, size_t ws_size,
                              hipStream_t stream) {
    const int nu = in_sizes[0] / 128;
    const int nm = in_sizes[1] / 128;
    const int E = in_sizes[2];

    const float* xu = (const float*)d_in[0];
    const float* xm = (const float*)d_in[1];
    const int* esrc = (const int*)d_in[2];
    const int* edst = (const int*)d_in[3];
    const float* Wl1_um = (const float*)d_in[4];
    const float* Wr1_um = (const float*)d_in[5];
    const float* Wl1_mu = (const float*)d_in[6];
    const float* Wr1_mu = (const float*)d_in[7];
    const float* Wl2_um = (const float*)d_in[8];
    const float* Wr2_um = (const float*)d_in[9];
    const float* Wl2_mu = (const float*)d_in[10];
    const float* Wr2_mu = (const float*)d_in[11];
    const float* b1_um = (const float*)d_in[12];
    const float* b1_mu = (const float*)d_in[13];
    const float* b2_um = (const float*)d_in[14];
    const float* b2_mu = (const float*)d_in[15];

    float* out_u = (float*)d_out;
    float* out_m = out_u + (size_t)nu * 128;

    // ---- workspace layout (~54 MB; >=62 MB available) ----
    const int ntot = nu + nm;
    const int NB = (ntot + 4095) / 4096;      // <=64 required by scan_apply
    int* cnt = (int*)d_ws;                     // ntot
    int* off = cnt + ntot;                     // ntot+1
    int* bsum = off + ntot + 1;                // NB (padded to 16)
    int* ranku = bsum + ((NB + 15) & ~15);     // E
    int* rankm = ranku + E;                    // E
    int* nbr = rankm + E;                      // 2E
    size_t int_bytes = (size_t)((nbr + 2 * (size_t)E) - (int*)d_ws) * 4;
    size_t wt_off = (int_bytes + 63) & ~(size_t)63;   // 16B-align for short8
    u16* wt1_um = (u16*)((char*)d_ws + wt_off);       // 4 stacks x 32768 u16
    u16* wt1_mu = wt1_um + 32768;
    u16* wt2_um = wt1_mu + 32768;
    u16* wt2_mu = wt2_um + 32768;
    // bf16 feature buffers. Abf holds xu_bf for layer 1, then is overwritten
    // with ru_bf by the L1-user dispatch (xu_bf's last consumer, L1-movie,
    // completes first in stream order).
    u32* Abf = (u32*)((char*)d_ws + wt_off + 4 * 65536);  // nu*64
    u32* xmb = Abf + (size_t)nu * 64;                     // nm*64
    u32* rmb = xmb + (size_t)nm * 64;                     // nm*64

    const int eg4 = (E + 1023) / 1024;
    const int cg = ((nu + nm) * 64 + 1023) / 1024;

    WPtrs wp;
    wp.wl[0] = Wl1_um; wp.wr[0] = Wr1_um; wp.wout[0] = wt1_um;
    wp.wl[1] = Wl1_mu; wp.wr[1] = Wr1_mu; wp.wout[1] = wt1_mu;
    wp.wl[2] = Wl2_um; wp.wr[2] = Wr2_um; wp.wout[2] = wt2_um;
    wp.wl[3] = Wl2_mu; wp.wr[3] = Wr2_mu; wp.wout[3] = wt2_mu;

    // ---- CSR build + prep (hist atomics dominate; conv/wprep ride free) ----
    hipMemsetAsync(cnt, 0, (size_t)ntot * 4, stream);
    prep_kernel<<<eg4 + cg + 64, 256, 0, stream>>>(
        esrc, edst, cnt, ranku, rankm, E, nu, nm, xu, xm, Abf, xmb, eg4, cg, wp);
    scan_partial<<<NB, 256, 0, stream>>>(cnt, bsum, ntot);
    scan_apply<<<NB, 256, 0, stream>>>(cnt, bsum, off, ntot, NB);
    fill_pos<<<eg4, 256, 0, stream>>>(esrc, edst, ranku, rankm, off, nbr, E, nu);

    const int gm = (nm + 15) / 16;
    const int gu = (nu + 15) / 16;

    // ---- layer 1 (bf16-only outputs) ----
    // movie: gather xu_bf (Abf), x = xm f32, write rm_bf
    fused_l1<<<gm, 128, 0, stream>>>(Abf, xm, off + nu, nbr, wt1_um, b1_um,
                                     rmb, nm);
    // user: gather xm_bf, x = xu f32, write ru_bf into Abf (xu_bf now dead)
    fused_l1<<<gu, 128, 0, stream>>>(xmb, xu, off, nbr, wt1_mu, b1_mu,
                                     Abf, nu);

    // ---- layer 2 merged (reads Abf/rmb only; writes d_out only) ----
    fused_l2_dual<<<gm + gu, 128, 0, stream>>>(
        Abf, rmb, off, nbr, wt2_um, wt2_mu, b2_um, b2_mu, out_m, out_u,
        nm, nu, gm);
}